// Round 1
// baseline (260.149 us; speedup 1.0000x reference)
//
#include <hip/hip_runtime.h>

#define NHEADS 6
#define HD 32
#define CDIM 192
#define NTOK 64
#define NREL 225
#define PDIM 12
#define IMG 256
#define NWW 32            // windows per row/col (256/8)
#define NWIN 2048         // 2 * 32 * 32
#define SCALE 0.17677669529663687f  // 32^-0.5

__device__ __forceinline__ void ln_relu12(const float* x, const float* g,
                                          const float* be, float* y) {
    float m = 0.f;
#pragma unroll
    for (int i = 0; i < PDIM; ++i) m += x[i];
    m *= (1.f / PDIM);
    float v = 0.f;
#pragma unroll
    for (int i = 0; i < PDIM; ++i) { float d = x[i] - m; v += d * d; }
    v *= (1.f / PDIM);
    float inv = rsqrtf(v + 1e-5f);
#pragma unroll
    for (int i = 0; i < PDIM; ++i) {
        float t = (x[i] - m) * inv * g[i] + be[i];
        y[i] = t > 0.f ? t : 0.f;
    }
}

__global__ __launch_bounds__(256) void posbias_mlp_kernel(
    const float* __restrict__ wp, const float* __restrict__ bp,
    const float* __restrict__ g1, const float* __restrict__ be1,
    const float* __restrict__ w1, const float* __restrict__ b1,
    const float* __restrict__ g2, const float* __restrict__ be2,
    const float* __restrict__ w2, const float* __restrict__ b2,
    const float* __restrict__ g3, const float* __restrict__ be3,
    const float* __restrict__ w3, const float* __restrict__ b3,
    float* __restrict__ p_out)
{
    int r = blockIdx.x * blockDim.x + threadIdx.x;
    if (r >= NREL) return;
    float x0 = (float)(r / 15 - 7);   // relative h offset
    float x1 = (float)(r % 15 - 7);   // relative w offset
    float h[PDIM], y[PDIM];
#pragma unroll
    for (int o = 0; o < PDIM; ++o)
        h[o] = x0 * wp[o] + x1 * wp[PDIM + o] + bp[o];
    ln_relu12(h, g1, be1, y);
#pragma unroll
    for (int o = 0; o < PDIM; ++o) {
        float a = b1[o];
#pragma unroll
        for (int i = 0; i < PDIM; ++i) a += y[i] * w1[i * PDIM + o];
        h[o] = a;
    }
    ln_relu12(h, g2, be2, y);
#pragma unroll
    for (int o = 0; o < PDIM; ++o) {
        float a = b2[o];
#pragma unroll
        for (int i = 0; i < PDIM; ++i) a += y[i] * w2[i * PDIM + o];
        h[o] = a;
    }
    ln_relu12(h, g3, be3, y);
#pragma unroll
    for (int o = 0; o < NHEADS; ++o) {
        float a = b3[o];
#pragma unroll
        for (int i = 0; i < PDIM; ++i) a += y[i] * w3[i * NHEADS + o];
        p_out[r * NHEADS + o] = a;
    }
}

__global__ __launch_bounds__(256) void win_attn_kernel(
    const float* __restrict__ qkv, const float* __restrict__ p,
    float* __restrict__ out)
{
    __shared__ float qs[NTOK][HD + 1];
    __shared__ float ks[NTOK][HD + 1];
    __shared__ float vs[NTOK][HD + 1];
    __shared__ float at[NTOK][NTOK + 1];
    __shared__ float pb[NREL];

    const int t = threadIdx.x;
    const int head = blockIdx.x % NHEADS;      // 6 consecutive blocks share a window
    const int win  = blockIdx.x / NHEADS;
    const int b    = win / (NWW * NWW);
    const int wrem = win % (NWW * NWW);
    const int bh   = wrem / NWW;
    const int bw   = wrem % NWW;

    // bias column for this head
    for (int i = t; i < NREL; i += 256) pb[i] = p[i * NHEADS + head];

    // stage q,k,v: 64 tokens x 32 floats each = 512 float4 per tensor
    const size_t SST = (size_t)2 * IMG * IMG * CDIM;  // stride between q/k/v planes
    const float* basep = qkv + (size_t)b * IMG * IMG * CDIM;
#pragma unroll
    for (int pass = 0; pass < 2; ++pass) {
        int idx = t + pass * 256;
        int tok = idx >> 3;           // 0..63
        int f4  = idx & 7;            // 0..7 (which float4 in the 32-float slice)
        int i1 = tok >> 3, j1 = tok & 7;
        size_t loff = ((size_t)(bh * 8 + i1) * IMG + (bw * 8 + j1)) * CDIM
                    + head * HD + f4 * 4;
        float4 q4 = *(const float4*)(basep + loff);
        float4 k4 = *(const float4*)(basep + SST + loff);
        float4 v4 = *(const float4*)(basep + 2 * SST + loff);
        int d = f4 * 4;
        qs[tok][d + 0] = q4.x * SCALE; qs[tok][d + 1] = q4.y * SCALE;
        qs[tok][d + 2] = q4.z * SCALE; qs[tok][d + 3] = q4.w * SCALE;
        ks[tok][d + 0] = k4.x; ks[tok][d + 1] = k4.y;
        ks[tok][d + 2] = k4.z; ks[tok][d + 3] = k4.w;
        vs[tok][d + 0] = v4.x; vs[tok][d + 1] = v4.y;
        vs[tok][d + 2] = v4.z; vs[tok][d + 3] = v4.w;
    }
    __syncthreads();

    // QK^T: each thread owns a 4x4 tile of the 64x64 score matrix
    {
        const int rq = (t >> 4) << 2;     // row base 0..60
        const int cq = (t & 15) << 2;     // col base 0..60
        float acc[4][4] = {};
        for (int d = 0; d < HD; ++d) {
            float qv[4], kv[4];
#pragma unroll
            for (int i = 0; i < 4; ++i) qv[i] = qs[rq + i][d];
#pragma unroll
            for (int j = 0; j < 4; ++j) kv[j] = ks[cq + j][d];
#pragma unroll
            for (int i = 0; i < 4; ++i)
#pragma unroll
                for (int j = 0; j < 4; ++j) acc[i][j] += qv[i] * kv[j];
        }
#pragma unroll
        for (int i = 0; i < 4; ++i)
#pragma unroll
            for (int j = 0; j < 4; ++j) at[rq + i][cq + j] = acc[i][j];
    }
    __syncthreads();

    // softmax: wave w handles rows w*16 .. w*16+15; lane = column
    {
        const int wave = t >> 6, lane = t & 63;
        const int i2 = lane >> 3, j2 = lane & 7;
#pragma unroll
        for (int rr = 0; rr < 16; ++rr) {
            int n = wave * 16 + rr;
            int i1 = n >> 3, j1 = n & 7;
            float x = at[n][lane] + pb[(i1 - i2 + 7) * 15 + (j1 - j2 + 7)];
            float mx = x;
#pragma unroll
            for (int off = 32; off; off >>= 1)
                mx = fmaxf(mx, __shfl_xor(mx, off));
            float e = expf(x - mx);
            float s = e;
#pragma unroll
            for (int off = 32; off; off >>= 1)
                s += __shfl_xor(s, off);
            at[n][lane] = e / s;
        }
    }
    __syncthreads();

    // PV: each thread owns 2 rows x 4 cols of the 64x32 output
    {
        const int tr = t >> 3;        // 0..31 -> rows 2tr, 2tr+1
        const int tc = t & 7;         // 0..7  -> cols 4tc..4tc+3
        float acc[2][4] = {};
        for (int m = 0; m < NTOK; ++m) {
            float a0 = at[2 * tr + 0][m];
            float a1 = at[2 * tr + 1][m];
#pragma unroll
            for (int cc = 0; cc < 4; ++cc) {
                float vv = vs[m][4 * tc + cc];
                acc[0][cc] += a0 * vv;
                acc[1][cc] += a1 * vv;
            }
        }
#pragma unroll
        for (int rr = 0; rr < 2; ++rr) {
            int n = 2 * tr + rr;
            int i1 = n >> 3, j1 = n & 7;
            size_t off = (((size_t)b * IMG + bh * 8 + i1) * IMG + (bw * 8 + j1)) * CDIM
                       + head * HD + 4 * tc;
            float4 o4 = make_float4(acc[rr][0], acc[rr][1], acc[rr][2], acc[rr][3]);
            *(float4*)(out + off) = o4;
        }
    }
}

extern "C" void kernel_launch(void* const* d_in, const int* in_sizes, int n_in,
                              void* d_out, int out_size, void* d_ws, size_t ws_size,
                              hipStream_t stream) {
    const float* qkv = (const float*)d_in[0];
    const float* wp  = (const float*)d_in[1];
    const float* bp  = (const float*)d_in[2];
    const float* g1  = (const float*)d_in[3];
    const float* be1 = (const float*)d_in[4];
    const float* w1  = (const float*)d_in[5];
    const float* b1  = (const float*)d_in[6];
    const float* g2  = (const float*)d_in[7];
    const float* be2 = (const float*)d_in[8];
    const float* w2  = (const float*)d_in[9];
    const float* b2  = (const float*)d_in[10];
    const float* g3  = (const float*)d_in[11];
    const float* be3 = (const float*)d_in[12];
    const float* w3  = (const float*)d_in[13];
    const float* b3  = (const float*)d_in[14];

    float* p_ws = (float*)d_ws;   // 225 * 6 floats
    posbias_mlp_kernel<<<1, 256, 0, stream>>>(wp, bp, g1, be1, w1, b1,
                                              g2, be2, w2, b2, g3, be3, w3, b3,
                                              p_ws);
    win_attn_kernel<<<NWIN * NHEADS, 256, 0, stream>>>(qkv, p_ws, (float*)d_out);
}

// Round 2
// 101.004 us; speedup vs baseline: 2.5756x; 2.5756x over previous
//
#include <hip/hip_runtime.h>

#define NHEADS 6
#define HD 32
#define CDIM 192
#define NTOK 64
#define NREL 225
#define PDIM 12
#define IMG 256
#define NWW 32
#define NWIN 2048
#define SCALE 0.17677669529663687f

typedef __attribute__((ext_vector_type(8))) short v8s;
typedef __attribute__((ext_vector_type(4))) float v4f;

// LDS strides (elements)
#define QKS 40   // qs/ks row stride in bf16 (64 rows)
#define VTS 72   // vt row stride in bf16 (32 rows = d)
#define ATS 68   // at row stride in f32 (64 rows)
#define PTS 72   // pt row stride in bf16 (aliases at)

__device__ __forceinline__ unsigned short f2bf(float f) {
    union { float f; unsigned u; } c; c.f = f;
    unsigned u = c.u + 0x7fffu + ((c.u >> 16) & 1u);
    return (unsigned short)(u >> 16);
}

__device__ __forceinline__ void ln_relu12(const float* x, const float* g,
                                          const float* be, float* y) {
    float m = 0.f;
#pragma unroll
    for (int i = 0; i < PDIM; ++i) m += x[i];
    m *= (1.f / PDIM);
    float v = 0.f;
#pragma unroll
    for (int i = 0; i < PDIM; ++i) { float d = x[i] - m; v += d * d; }
    v *= (1.f / PDIM);
    float inv = rsqrtf(v + 1e-5f);
#pragma unroll
    for (int i = 0; i < PDIM; ++i) {
        float t = (x[i] - m) * inv * g[i] + be[i];
        y[i] = t > 0.f ? t : 0.f;
    }
}

// One block: compute 225x6 MLP then expand to rpb[6][64][64]
__global__ __launch_bounds__(256) void posbias_kernel(
    const float* __restrict__ wp, const float* __restrict__ bp,
    const float* __restrict__ g1, const float* __restrict__ be1,
    const float* __restrict__ w1, const float* __restrict__ b1,
    const float* __restrict__ g2, const float* __restrict__ be2,
    const float* __restrict__ w2, const float* __restrict__ b2,
    const float* __restrict__ g3, const float* __restrict__ be3,
    const float* __restrict__ w3, const float* __restrict__ b3,
    float* __restrict__ rpb)
{
    __shared__ float p_sh[NREL * NHEADS];
    int r = threadIdx.x;
    if (r < NREL) {
        float x0 = (float)(r / 15 - 7);
        float x1 = (float)(r % 15 - 7);
        float h[PDIM], y[PDIM];
#pragma unroll
        for (int o = 0; o < PDIM; ++o)
            h[o] = x0 * wp[o] + x1 * wp[PDIM + o] + bp[o];
        ln_relu12(h, g1, be1, y);
#pragma unroll
        for (int o = 0; o < PDIM; ++o) {
            float a = b1[o];
#pragma unroll
            for (int i = 0; i < PDIM; ++i) a += y[i] * w1[i * PDIM + o];
            h[o] = a;
        }
        ln_relu12(h, g2, be2, y);
#pragma unroll
        for (int o = 0; o < PDIM; ++o) {
            float a = b2[o];
#pragma unroll
            for (int i = 0; i < PDIM; ++i) a += y[i] * w2[i * PDIM + o];
            h[o] = a;
        }
        ln_relu12(h, g3, be3, y);
#pragma unroll
        for (int o = 0; o < NHEADS; ++o) {
            float a = b3[o];
#pragma unroll
            for (int i = 0; i < PDIM; ++i) a += y[i] * w3[i * NHEADS + o];
            p_sh[r * NHEADS + o] = a;
        }
    }
    __syncthreads();
    for (int i = threadIdx.x; i < NHEADS * NTOK * NTOK; i += 256) {
        int h = i >> 12;
        int n = (i >> 6) & 63;
        int m = i & 63;
        int idx = ((n >> 3) - (m >> 3) + 7) * 15 + ((n & 7) - (m & 7) + 7);
        rpb[i] = p_sh[idx * NHEADS + h];
    }
}

__global__ __launch_bounds__(256) void win_attn_mfma(
    const float* __restrict__ qkv, const float* __restrict__ rpb,
    float* __restrict__ out)
{
    __shared__ unsigned short qs[NTOK * QKS];
    __shared__ unsigned short ks[NTOK * QKS];
    __shared__ unsigned short vt[HD * VTS];
    __shared__ float at[NTOK * ATS];           // S (f32); later aliased by P (bf16)
    unsigned short* pt = (unsigned short*)at;  // P, 64 x PTS bf16 (9216B <= 17408B)

    const int t = threadIdx.x;
    // head-major ordering: consecutive blocks share the head's 16KB rpb tile (L1)
    const int head = blockIdx.x >> 11;
    const int win  = blockIdx.x & (NWIN - 1);
    const int b    = win >> 10;
    const int bh   = (win >> 5) & 31;
    const int bw   = win & 31;

    // ---- stage q,k (row-major bf16) and v (transposed bf16) ----
    const size_t SST = (size_t)2 * IMG * IMG * CDIM;
    const float* basep = qkv + (size_t)b * IMG * IMG * CDIM;
#pragma unroll
    for (int pass = 0; pass < 2; ++pass) {
        int idx = t + pass * 256;
        int tok = idx >> 3;
        int d   = (idx & 7) * 4;
        size_t loff = ((size_t)(bh * 8 + (tok >> 3)) * IMG + (bw * 8 + (tok & 7))) * CDIM
                    + head * HD + d;
        float4 q4 = *(const float4*)(basep + loff);
        float4 k4 = *(const float4*)(basep + SST + loff);
        float4 v4 = *(const float4*)(basep + 2 * SST + loff);
        *(ushort4*)&qs[tok * QKS + d] = make_ushort4(
            f2bf(q4.x * SCALE), f2bf(q4.y * SCALE), f2bf(q4.z * SCALE), f2bf(q4.w * SCALE));
        *(ushort4*)&ks[tok * QKS + d] = make_ushort4(
            f2bf(k4.x), f2bf(k4.y), f2bf(k4.z), f2bf(k4.w));
        vt[(d + 0) * VTS + tok] = f2bf(v4.x);
        vt[(d + 1) * VTS + tok] = f2bf(v4.y);
        vt[(d + 2) * VTS + tok] = f2bf(v4.z);
        vt[(d + 3) * VTS + tok] = f2bf(v4.w);
    }
    __syncthreads();

    const int wave = t >> 6;
    const int lane = t & 63;
    const int lw = lane & 15;
    const int lg = lane >> 4;
    const int rowbase = wave * 16;

    // ---- S = Q K^T + rpb via MFMA (each wave: rows [rowbase,rowbase+16)) ----
    {
        const float* rpbh = rpb + head * NTOK * NTOK;
        v8s a = *(const v8s*)&qs[(rowbase + lw) * QKS + lg * 8];
        v4f acc[4];
#pragma unroll
        for (int ct = 0; ct < 4; ++ct) {
#pragma unroll
            for (int r = 0; r < 4; ++r)
                acc[ct][r] = rpbh[(rowbase + lg * 4 + r) * NTOK + ct * 16 + lw];
            v8s bfr = *(const v8s*)&ks[(ct * 16 + lw) * QKS + lg * 8];
            acc[ct] = __builtin_amdgcn_mfma_f32_16x16x32_bf16(a, bfr, acc[ct], 0, 0, 0);
        }
#pragma unroll
        for (int ct = 0; ct < 4; ++ct)
#pragma unroll
            for (int r = 0; r < 4; ++r)
                at[(rowbase + lg * 4 + r) * ATS + ct * 16 + lw] = acc[ct][r];
    }
    __syncthreads();

    // ---- softmax: thread owns (row = t>>2, cols (t&3)*16 .. +15) ----
    {
        const int r  = t >> 2;
        const int cb = (t & 3) * 16;
        float x[16];
#pragma unroll
        for (int kk = 0; kk < 4; ++kk) {
            float4 x4 = *(const float4*)&at[r * ATS + cb + 4 * kk];
            x[4 * kk + 0] = x4.x; x[4 * kk + 1] = x4.y;
            x[4 * kk + 2] = x4.z; x[4 * kk + 3] = x4.w;
        }
        float mx = x[0];
#pragma unroll
        for (int i = 1; i < 16; ++i) mx = fmaxf(mx, x[i]);
        mx = fmaxf(mx, __shfl_xor(mx, 1));
        mx = fmaxf(mx, __shfl_xor(mx, 2));
        float s = 0.f;
#pragma unroll
        for (int i = 0; i < 16; ++i) { x[i] = __expf(x[i] - mx); s += x[i]; }
        s += __shfl_xor(s, 1);
        s += __shfl_xor(s, 2);
        float rinv = 1.f / s;
        v8s pw0, pw1;
#pragma unroll
        for (int i = 0; i < 8; ++i) pw0[i] = (short)f2bf(x[i] * rinv);
#pragma unroll
        for (int i = 0; i < 8; ++i) pw1[i] = (short)f2bf(x[8 + i] * rinv);
        __syncthreads();   // all S reads done before aliased P writes
        *(v8s*)&pt[r * PTS + cb]     = pw0;
        *(v8s*)&pt[r * PTS + cb + 8] = pw1;
    }
    __syncthreads();

    // ---- O = P V via MFMA ----
    {
        v8s pa[2];
#pragma unroll
        for (int kt = 0; kt < 2; ++kt)
            pa[kt] = *(const v8s*)&pt[(rowbase + lw) * PTS + kt * 32 + lg * 8];
        v4f acc2[2] = {};
#pragma unroll
        for (int dt = 0; dt < 2; ++dt)
#pragma unroll
            for (int kt = 0; kt < 2; ++kt) {
                v8s vb = *(const v8s*)&vt[(dt * 16 + lw) * VTS + kt * 32 + lg * 8];
                acc2[dt] = __builtin_amdgcn_mfma_f32_16x16x32_bf16(pa[kt], vb, acc2[dt], 0, 0, 0);
            }
#pragma unroll
        for (int dt = 0; dt < 2; ++dt)
#pragma unroll
            for (int r = 0; r < 4; ++r) {
                int n = rowbase + lg * 4 + r;
                size_t off = (((size_t)b * IMG + bh * 8 + (n >> 3)) * IMG
                              + (bw * 8 + (n & 7))) * CDIM + head * HD + dt * 16 + lw;
                out[off] = acc2[dt][r];
            }
    }
}

extern "C" void kernel_launch(void* const* d_in, const int* in_sizes, int n_in,
                              void* d_out, int out_size, void* d_ws, size_t ws_size,
                              hipStream_t stream) {
    const float* qkv = (const float*)d_in[0];
    const float* wp  = (const float*)d_in[1];
    const float* bp  = (const float*)d_in[2];
    const float* g1  = (const float*)d_in[3];
    const float* be1 = (const float*)d_in[4];
    const float* w1  = (const float*)d_in[5];
    const float* b1  = (const float*)d_in[6];
    const float* g2  = (const float*)d_in[7];
    const float* be2 = (const float*)d_in[8];
    const float* w2  = (const float*)d_in[9];
    const float* b2  = (const float*)d_in[10];
    const float* g3  = (const float*)d_in[11];
    const float* be3 = (const float*)d_in[12];
    const float* w3  = (const float*)d_in[13];
    const float* b3  = (const float*)d_in[14];

    float* rpb = (float*)d_ws;  // 6*64*64 floats = 96KB
    posbias_kernel<<<1, 256, 0, stream>>>(wp, bp, g1, be1, w1, b1,
                                          g2, be2, w2, b2, g3, be3, w3, b3, rpb);
    win_attn_mfma<<<NWIN * NHEADS, 256, 0, stream>>>(qkv, rpb, (float*)d_out);
}

// Round 3
// 96.754 us; speedup vs baseline: 2.6888x; 1.0439x over previous
//
#include <hip/hip_runtime.h>

#define NHEADS 6
#define HD 32
#define CDIM 192
#define NTOK 64
#define NREL 225
#define PDIM 12
#define IMG 256
#define NWW 32
#define NWIN 2048
#define SCALE 0.17677669529663687f

typedef __attribute__((ext_vector_type(8))) short v8s;
typedef __attribute__((ext_vector_type(4))) float v4f;

// LDS strides (elements); row byte-strides must be 16B-aligned for b128 access
#define QKS 40   // qs/ks row stride bf16 (80B)
#define VTS 72   // vt row stride bf16 (144B)
#define PTS 72   // pt row stride bf16 (144B)

__device__ __forceinline__ unsigned short f2bf(float f) {
    union { float f; unsigned u; } c; c.f = f;
    unsigned u = c.u + 0x7fffu + ((c.u >> 16) & 1u);
    return (unsigned short)(u >> 16);
}

__device__ __forceinline__ void ln_relu12(const float* x, const float* g,
                                          const float* be, float* y) {
    float m = 0.f;
#pragma unroll
    for (int i = 0; i < PDIM; ++i) m += x[i];
    m *= (1.f / PDIM);
    float v = 0.f;
#pragma unroll
    for (int i = 0; i < PDIM; ++i) { float d = x[i] - m; v += d * d; }
    v *= (1.f / PDIM);
    float inv = rsqrtf(v + 1e-5f);
#pragma unroll
    for (int i = 0; i < PDIM; ++i) {
        float t = (x[i] - m) * inv * g[i] + be[i];
        y[i] = t > 0.f ? t : 0.f;
    }
}

// grid=96 blocks; each block recomputes the tiny MLP (threads 0..224), then
// writes its 256-element slice of rpb[6][64][64] (parallel expansion).
__global__ __launch_bounds__(256) void posbias_kernel(
    const float* __restrict__ wp, const float* __restrict__ bp,
    const float* __restrict__ g1, const float* __restrict__ be1,
    const float* __restrict__ w1, const float* __restrict__ b1,
    const float* __restrict__ g2, const float* __restrict__ be2,
    const float* __restrict__ w2, const float* __restrict__ b2,
    const float* __restrict__ g3, const float* __restrict__ be3,
    const float* __restrict__ w3, const float* __restrict__ b3,
    float* __restrict__ rpb)
{
    __shared__ float p_sh[NREL * NHEADS];
    int r = threadIdx.x;
    if (r < NREL) {
        float x0 = (float)(r / 15 - 7);
        float x1 = (float)(r % 15 - 7);
        float h[PDIM], y[PDIM];
#pragma unroll
        for (int o = 0; o < PDIM; ++o)
            h[o] = x0 * wp[o] + x1 * wp[PDIM + o] + bp[o];
        ln_relu12(h, g1, be1, y);
#pragma unroll
        for (int o = 0; o < PDIM; ++o) {
            float a = b1[o];
#pragma unroll
            for (int i = 0; i < PDIM; ++i) a += y[i] * w1[i * PDIM + o];
            h[o] = a;
        }
        ln_relu12(h, g2, be2, y);
#pragma unroll
        for (int o = 0; o < PDIM; ++o) {
            float a = b2[o];
#pragma unroll
            for (int i = 0; i < PDIM; ++i) a += y[i] * w2[i * PDIM + o];
            h[o] = a;
        }
        ln_relu12(h, g3, be3, y);
#pragma unroll
        for (int o = 0; o < NHEADS; ++o) {
            float a = b3[o];
#pragma unroll
            for (int i = 0; i < PDIM; ++i) a += y[i] * w3[i * NHEADS + o];
            p_sh[r * NHEADS + o] = a;
        }
    }
    __syncthreads();
    int i = blockIdx.x * 256 + threadIdx.x;   // 96*256 = 24576 = 6*64*64
    int h = i >> 12;
    int n = (i >> 6) & 63;
    int m = i & 63;
    int idx = ((n >> 3) - (m >> 3) + 7) * 15 + ((n & 7) - (m & 7) + 7);
    rpb[i] = p_sh[idx * NHEADS + h];
}

__global__ __launch_bounds__(256) void win_attn_mfma(
    const float* __restrict__ qkv, const float* __restrict__ rpb,
    float* __restrict__ out)
{
    __shared__ unsigned short qs[NTOK * QKS];
    __shared__ unsigned short ks[NTOK * QKS];
    __shared__ unsigned short vt[HD * VTS];
    __shared__ unsigned short pt[NTOK * PTS];

    const int t = threadIdx.x;
    // head-major: 2048 consecutive blocks share one 16KB rpb head tile (L1/L2)
    const int head = blockIdx.x >> 11;
    const int win  = blockIdx.x & (NWIN - 1);
    const int b    = win >> 10;
    const int bh   = (win >> 5) & 31;
    const int bw   = win & 31;

    const int wave = t >> 6;
    const int lane = t & 63;
    const int lw = lane & 15;
    const int lg = lane >> 4;
    const int rowbase = wave * 16;

    // ---- hoist rpb C-input gather (L1-resident; overlaps staging below) ----
    float rbias[4][4];
    {
        const float* rpbh = rpb + head * NTOK * NTOK;
#pragma unroll
        for (int ct = 0; ct < 4; ++ct)
#pragma unroll
            for (int r = 0; r < 4; ++r)
                rbias[ct][r] = rpbh[(rowbase + lg * 4 + r) * NTOK + ct * 16 + lw];
    }

    // ---- stage q,k (row-major bf16) and v (transposed bf16) ----
    const size_t SST = (size_t)2 * IMG * IMG * CDIM;
    const float* basep = qkv + (size_t)b * IMG * IMG * CDIM;
#pragma unroll
    for (int pass = 0; pass < 2; ++pass) {
        int idx = t + pass * 256;
        int tok = idx >> 3;
        int d   = (idx & 7) * 4;
        size_t loff = ((size_t)(bh * 8 + (tok >> 3)) * IMG + (bw * 8 + (tok & 7))) * CDIM
                    + head * HD + d;
        float4 q4 = *(const float4*)(basep + loff);
        float4 k4 = *(const float4*)(basep + SST + loff);
        float4 v4 = *(const float4*)(basep + 2 * SST + loff);
        *(ushort4*)&qs[tok * QKS + d] = make_ushort4(
            f2bf(q4.x * SCALE), f2bf(q4.y * SCALE), f2bf(q4.z * SCALE), f2bf(q4.w * SCALE));
        *(ushort4*)&ks[tok * QKS + d] = make_ushort4(
            f2bf(k4.x), f2bf(k4.y), f2bf(k4.z), f2bf(k4.w));
        vt[(d + 0) * VTS + tok] = f2bf(v4.x);
        vt[(d + 1) * VTS + tok] = f2bf(v4.y);
        vt[(d + 2) * VTS + tok] = f2bf(v4.z);
        vt[(d + 3) * VTS + tok] = f2bf(v4.w);
    }
    __syncthreads();

    // ---- S = Q K^T + rpb via MFMA; softmax fully in-register ----
    {
        v8s a = *(const v8s*)&qs[(rowbase + lw) * QKS + lg * 8];
        v4f acc[4];
#pragma unroll
        for (int ct = 0; ct < 4; ++ct) {
#pragma unroll
            for (int r = 0; r < 4; ++r) acc[ct][r] = rbias[ct][r];
            v8s bfr = *(const v8s*)&ks[(ct * 16 + lw) * QKS + lg * 8];
            acc[ct] = __builtin_amdgcn_mfma_f32_16x16x32_bf16(a, bfr, acc[ct], 0, 0, 0);
        }
        // row max: elementwise over ct, then xor-reduce across the 16-lane group
        v4f mx4;
#pragma unroll
        for (int r = 0; r < 4; ++r)
            mx4[r] = fmaxf(fmaxf(acc[0][r], acc[1][r]), fmaxf(acc[2][r], acc[3][r]));
#pragma unroll
        for (int off = 1; off < 16; off <<= 1)
#pragma unroll
            for (int r = 0; r < 4; ++r)
                mx4[r] = fmaxf(mx4[r], __shfl_xor(mx4[r], off));
        // exp + row sum
        v4f s4 = {0.f, 0.f, 0.f, 0.f};
#pragma unroll
        for (int ct = 0; ct < 4; ++ct)
#pragma unroll
            for (int r = 0; r < 4; ++r) {
                acc[ct][r] = __expf(acc[ct][r] - mx4[r]);
                s4[r] += acc[ct][r];
            }
#pragma unroll
        for (int off = 1; off < 16; off <<= 1)
#pragma unroll
            for (int r = 0; r < 4; ++r)
                s4[r] += __shfl_xor(s4[r], off);
        v4f rinv;
#pragma unroll
        for (int r = 0; r < 4; ++r) rinv[r] = 1.f / s4[r];
        // write P (bf16) straight from accumulator layout
#pragma unroll
        for (int ct = 0; ct < 4; ++ct)
#pragma unroll
            for (int r = 0; r < 4; ++r)
                pt[(rowbase + lg * 4 + r) * PTS + ct * 16 + lw] =
                    f2bf(acc[ct][r] * rinv[r]);
    }
    __syncthreads();

    // ---- O = P V via MFMA ----
    {
        v8s pa[2];
#pragma unroll
        for (int kt = 0; kt < 2; ++kt)
            pa[kt] = *(const v8s*)&pt[(rowbase + lw) * PTS + kt * 32 + lg * 8];
        v4f acc2[2] = {};
#pragma unroll
        for (int dt = 0; dt < 2; ++dt)
#pragma unroll
            for (int kt = 0; kt < 2; ++kt) {
                v8s vb = *(const v8s*)&vt[(dt * 16 + lw) * VTS + kt * 32 + lg * 8];
                acc2[dt] = __builtin_amdgcn_mfma_f32_16x16x32_bf16(pa[kt], vb, acc2[dt], 0, 0, 0);
            }
#pragma unroll
        for (int dt = 0; dt < 2; ++dt)
#pragma unroll
            for (int r = 0; r < 4; ++r) {
                int n = rowbase + lg * 4 + r;
                size_t off = (((size_t)b * IMG + bh * 8 + (n >> 3)) * IMG
                              + (bw * 8 + (n & 7))) * CDIM + head * HD + dt * 16 + lw;
                out[off] = acc2[dt][r];
            }
    }
}

extern "C" void kernel_launch(void* const* d_in, const int* in_sizes, int n_in,
                              void* d_out, int out_size, void* d_ws, size_t ws_size,
                              hipStream_t stream) {
    const float* qkv = (const float*)d_in[0];
    const float* wp  = (const float*)d_in[1];
    const float* bp  = (const float*)d_in[2];
    const float* g1  = (const float*)d_in[3];
    const float* be1 = (const float*)d_in[4];
    const float* w1  = (const float*)d_in[5];
    const float* b1  = (const float*)d_in[6];
    const float* g2  = (const float*)d_in[7];
    const float* be2 = (const float*)d_in[8];
    const float* w2  = (const float*)d_in[9];
    const float* b2  = (const float*)d_in[10];
    const float* g3  = (const float*)d_in[11];
    const float* be3 = (const float*)d_in[12];
    const float* w3  = (const float*)d_in[13];
    const float* b3  = (const float*)d_in[14];

    float* rpb = (float*)d_ws;  // 6*64*64 floats = 96KB
    posbias_kernel<<<96, 256, 0, stream>>>(wp, bp, g1, be1, w1, b1,
                                           g2, be2, w2, b2, g3, be3, w3, b3, rpb);
    win_attn_mfma<<<NWIN * NHEADS, 256, 0, stream>>>(qkv, rpb, (float*)d_out);
}